// Round 2
// baseline (226.859 us; speedup 1.0000x reference)
//
#include <hip/hip_runtime.h>

// ---------------------------------------------------------------------------
// 2-layer tanh RNN, B=8192, S=512, H=16, input=1, output=1.
// Layout: 16 lanes per batch element (lane = hidden unit index).
// 16x16 matvecs via DPP row_ror rotations. DPP row_ror:K => lane i reads
// lane (i-K)&15, so at step k lane holds h[(lane-k)&15] and the matching
// pre-permuted weight is w[k] = W[lane][(lane-k)&15].
// 512 threads/block, 256 blocks -> 8192 batches, 2048 waves (2/SIMD).
// ---------------------------------------------------------------------------

#define ROTF(v, K) __int_as_float(__builtin_amdgcn_update_dpp( \
    0, __float_as_int(v), 0x120 + (K), 0xF, 0xF, true))

__device__ __forceinline__ float tanh_fast(float v) {
    // tanh(v) = 1 - 2/(exp(2v)+1), exp via v_exp_f32 (2^x): 2*log2(e)=2.885390
    float e = __builtin_amdgcn_exp2f(v * 2.8853900817779268f);
    float r = __builtin_amdgcn_rcpf(e + 1.0f);
    return fmaf(-2.0f, r, 1.0f);
}

// one pair of rotated FMAs into two accumulator chains
#define MV_PAIR(acc0, acc1, hsrc, w, K0, K1)              \
    acc0 = fmaf(ROTF(hsrc, K0), (w)[K0], acc0);           \
    acc1 = fmaf(ROTF(hsrc, K1), (w)[K1], acc1);

__global__ __launch_bounds__(512, 2) void rnn2_kernel(
    const float* __restrict__ x,
    const float* __restrict__ Wih0, const float* __restrict__ Whh0,
    const float* __restrict__ bih0, const float* __restrict__ bhh0,
    const float* __restrict__ Wih1, const float* __restrict__ Whh1,
    const float* __restrict__ bih1, const float* __restrict__ bhh1,
    const float* __restrict__ Wfc,  const float* __restrict__ bfc,
    float* __restrict__ out)
{
    const int tid  = threadIdx.x;
    const int lane = tid & 15;
    const int b    = blockIdx.x * 32 + (tid >> 4);

    // Pre-permuted per-lane weight rows (rotation-matched ordering).
    // At rotation k this lane holds h[(lane-k)&15]  =>  w[k] = W[lane][(lane-k)&15].
    float w0[16], w1[16], w2[16];
#pragma unroll
    for (int k = 0; k < 16; ++k) {
        const int j = (lane - k) & 15;
        w0[k] = Whh0[lane * 16 + j];   // h0 @ W_hh0^T
        w1[k] = Wih1[lane * 16 + j];   // h0n @ W_ih1^T
        w2[k] = Whh1[lane * 16 + j];   // h1 @ W_hh1^T
    }
    const float wih0  = Wih0[lane];            // W_ih0 is [16][1]
    const float bias0 = bih0[lane] + bhh0[lane];
    const float bias1 = bih1[lane] + bhh1[lane];

    float h0 = 0.0f, h1 = 0.0f;
    const float* xb = x + (size_t)b * 512;

    for (int t0 = 0; t0 < 512; t0 += 16) {
        // all 16 lanes of a group load the same 16 x values (broadcast)
        const float4* xp = reinterpret_cast<const float4*>(xb + t0);
        const float4 q0 = xp[0], q1 = xp[1], q2 = xp[2], q3 = xp[3];
        const float xv[16] = {q0.x, q0.y, q0.z, q0.w, q1.x, q1.y, q1.z, q1.w,
                              q2.x, q2.y, q2.z, q2.w, q3.x, q3.y, q3.z, q3.w};
#pragma unroll
        for (int j = 0; j < 16; ++j) {
            const float xt = xv[j];
            // --- hh0 matvec (reads h0) and hh1 matvec (reads h1), interleaved
            float a0 = fmaf(h0, w0[0], fmaf(xt, wih0, bias0));
            float a1 = ROTF(h0, 1) * w0[1];
            float c0 = fmaf(h1, w2[0], bias1);
            float c1 = ROTF(h1, 1) * w2[1];
            MV_PAIR(a0, a1, h0, w0, 2, 3)
            MV_PAIR(c0, c1, h1, w2, 2, 3)
            MV_PAIR(a0, a1, h0, w0, 4, 5)
            MV_PAIR(c0, c1, h1, w2, 4, 5)
            MV_PAIR(a0, a1, h0, w0, 6, 7)
            MV_PAIR(c0, c1, h1, w2, 6, 7)
            MV_PAIR(a0, a1, h0, w0, 8, 9)
            MV_PAIR(c0, c1, h1, w2, 8, 9)
            MV_PAIR(a0, a1, h0, w0, 10, 11)
            MV_PAIR(c0, c1, h1, w2, 10, 11)
            MV_PAIR(a0, a1, h0, w0, 12, 13)
            MV_PAIR(c0, c1, h1, w2, 12, 13)
            MV_PAIR(a0, a1, h0, w0, 14, 15)
            MV_PAIR(c0, c1, h1, w2, 14, 15)

            const float h0n = tanh_fast(a0 + a1);

            // --- ih1 matvec (reads freshly computed h0n)
            float d0 = fmaf(h0n, w1[0], c0 + c1);
            float d1 = ROTF(h0n, 1) * w1[1];
            MV_PAIR(d0, d1, h0n, w1, 2, 3)
            MV_PAIR(d0, d1, h0n, w1, 4, 5)
            MV_PAIR(d0, d1, h0n, w1, 6, 7)
            MV_PAIR(d0, d1, h0n, w1, 8, 9)
            MV_PAIR(d0, d1, h0n, w1, 10, 11)
            MV_PAIR(d0, d1, h0n, w1, 12, 13)
            MV_PAIR(d0, d1, h0n, w1, 14, 15)

            h1 = tanh_fast(d0 + d1);
            h0 = h0n;
        }
    }

    // out[b] = h1 . W_fc + b_fc  — rotation-based 16-lane reduction
    // (rotations by 8,4,2,1 cover all 16 offsets; every lane ends with the sum)
    float v = h1 * Wfc[lane];
    v += ROTF(v, 8);
    v += ROTF(v, 4);
    v += ROTF(v, 2);
    v += ROTF(v, 1);
    if (lane == 0) out[b] = v + bfc[0];
}

extern "C" void kernel_launch(void* const* d_in, const int* in_sizes, int n_in,
                              void* d_out, int out_size, void* d_ws, size_t ws_size,
                              hipStream_t stream) {
    const float* x    = (const float*)d_in[0];
    const float* Wih0 = (const float*)d_in[1];
    const float* Whh0 = (const float*)d_in[2];
    const float* bih0 = (const float*)d_in[3];
    const float* bhh0 = (const float*)d_in[4];
    const float* Wih1 = (const float*)d_in[5];
    const float* Whh1 = (const float*)d_in[6];
    const float* bih1 = (const float*)d_in[7];
    const float* bhh1 = (const float*)d_in[8];
    const float* Wfc  = (const float*)d_in[9];
    const float* bfc  = (const float*)d_in[10];
    float* out = (float*)d_out;

    rnn2_kernel<<<dim3(256), dim3(512), 0, stream>>>(
        x, Wih0, Whh0, bih0, bhh0, Wih1, Whh1, bih1, bhh1, Wfc, bfc, out);
}

// Round 3
// 202.599 us; speedup vs baseline: 1.1197x; 1.1197x over previous
//
#include <hip/hip_runtime.h>

// ---------------------------------------------------------------------------
// 2-layer tanh RNN, B=8192, S=512, H=16, input=1, output=1.
// 16 lanes per batch element (lane = hidden unit). 16x16 matvecs as inline-asm
// v_fmac_f32_dpp row_ror:k chains (DPP folded into the FMA, no movs, no
// scratch). Weight permutation w[k] = W[lane][(lane-k)&15] matches row_ror:k
// (verified passing in round 2 with the same ctrl values 0x120+k).
// 512 threads/block, 256 blocks -> 2048 waves (2/SIMD over 256 CUs).
// ---------------------------------------------------------------------------

#define ROTF(v, K) __int_as_float(__builtin_amdgcn_update_dpp( \
    0, __float_as_int(v), 0x120 + (K), 0xF, 0xF, true))

__device__ __forceinline__ float tanh_fast(float v) {
    // tanh(v) = 1 - 2/(exp(2v)+1); exp via v_exp_f32 (2^x): 2*log2(e)
    float e = __builtin_amdgcn_exp2f(v * 2.8853900817779268f);
    float r = __builtin_amdgcn_rcpf(e + 1.0f);
    return fmaf(-2.0f, r, 1.0f);
}

#define DPPM "row_mask:0xf bank_mask:0xf"

// acc0+acc1 = sum_k rot_k(h)*W_k + init, rot_k(h)[lane]=h[(lane-k)&15].
// s_nop 1 + leading non-DPP VOP3 cover the 2-waitstate VALU-write -> DPP-read
// hazard on h (inline asm is opaque to the compiler's hazard recognizer).
#define MATVEC(acc0, acc1, h, W, init)                                        \
  asm volatile(                                                               \
      "s_nop 1\n\t"                                                           \
      "v_fma_f32 %0, %18, %2, %19\n\t"                                        \
      "v_mul_f32_dpp %1, %18, %3 row_ror:1 " DPPM "\n\t"                      \
      "v_fmac_f32_dpp %0, %18, %4 row_ror:2 " DPPM "\n\t"                     \
      "v_fmac_f32_dpp %1, %18, %5 row_ror:3 " DPPM "\n\t"                     \
      "v_fmac_f32_dpp %0, %18, %6 row_ror:4 " DPPM "\n\t"                     \
      "v_fmac_f32_dpp %1, %18, %7 row_ror:5 " DPPM "\n\t"                     \
      "v_fmac_f32_dpp %0, %18, %8 row_ror:6 " DPPM "\n\t"                     \
      "v_fmac_f32_dpp %1, %18, %9 row_ror:7 " DPPM "\n\t"                     \
      "v_fmac_f32_dpp %0, %18, %10 row_ror:8 " DPPM "\n\t"                    \
      "v_fmac_f32_dpp %1, %18, %11 row_ror:9 " DPPM "\n\t"                    \
      "v_fmac_f32_dpp %0, %18, %12 row_ror:10 " DPPM "\n\t"                   \
      "v_fmac_f32_dpp %1, %18, %13 row_ror:11 " DPPM "\n\t"                   \
      "v_fmac_f32_dpp %0, %18, %14 row_ror:12 " DPPM "\n\t"                   \
      "v_fmac_f32_dpp %1, %18, %15 row_ror:13 " DPPM "\n\t"                   \
      "v_fmac_f32_dpp %0, %18, %16 row_ror:14 " DPPM "\n\t"                   \
      "v_fmac_f32_dpp %1, %18, %17 row_ror:15 " DPPM                         \
      : "=&v"(acc0), "=&v"(acc1)                                              \
      : "v"(W##_0), "v"(W##_1), "v"(W##_2), "v"(W##_3), "v"(W##_4),           \
        "v"(W##_5), "v"(W##_6), "v"(W##_7), "v"(W##_8), "v"(W##_9),           \
        "v"(W##_10), "v"(W##_11), "v"(W##_12), "v"(W##_13), "v"(W##_14),      \
        "v"(W##_15), "v"(h), "v"(init));

// 16 individually named weights -> guaranteed VGPRs, no scratch-able array.
#define LOADW(NAME, SRC)                                          \
  const float NAME##_0  = (SRC)[lane * 16 + ((lane -  0) & 15)];  \
  const float NAME##_1  = (SRC)[lane * 16 + ((lane -  1) & 15)];  \
  const float NAME##_2  = (SRC)[lane * 16 + ((lane -  2) & 15)];  \
  const float NAME##_3  = (SRC)[lane * 16 + ((lane -  3) & 15)];  \
  const float NAME##_4  = (SRC)[lane * 16 + ((lane -  4) & 15)];  \
  const float NAME##_5  = (SRC)[lane * 16 + ((lane -  5) & 15)];  \
  const float NAME##_6  = (SRC)[lane * 16 + ((lane -  6) & 15)];  \
  const float NAME##_7  = (SRC)[lane * 16 + ((lane -  7) & 15)];  \
  const float NAME##_8  = (SRC)[lane * 16 + ((lane -  8) & 15)];  \
  const float NAME##_9  = (SRC)[lane * 16 + ((lane -  9) & 15)];  \
  const float NAME##_10 = (SRC)[lane * 16 + ((lane - 10) & 15)];  \
  const float NAME##_11 = (SRC)[lane * 16 + ((lane - 11) & 15)];  \
  const float NAME##_12 = (SRC)[lane * 16 + ((lane - 12) & 15)];  \
  const float NAME##_13 = (SRC)[lane * 16 + ((lane - 13) & 15)];  \
  const float NAME##_14 = (SRC)[lane * 16 + ((lane - 14) & 15)];  \
  const float NAME##_15 = (SRC)[lane * 16 + ((lane - 15) & 15)];

#define STEP(xt)                                         \
  {                                                      \
    const float a_init = fmaf((xt), wih0, bias0);        \
    float a0, a1, c0, c1, d0, d1;                        \
    MATVEC(a0, a1, h0, W0, a_init)                       \
    MATVEC(c0, c1, h1, W2, bias1)                        \
    const float h0n = tanh_fast(a0 + a1);                \
    const float cinit = c0 + c1;                         \
    MATVEC(d0, d1, h0n, W1, cinit)                       \
    h1 = tanh_fast(d0 + d1);                             \
    h0 = h0n;                                            \
  }

__global__ __launch_bounds__(512, 2) void rnn2_kernel(
    const float* __restrict__ x,
    const float* __restrict__ Wih0, const float* __restrict__ Whh0,
    const float* __restrict__ bih0, const float* __restrict__ bhh0,
    const float* __restrict__ Wih1, const float* __restrict__ Whh1,
    const float* __restrict__ bih1, const float* __restrict__ bhh1,
    const float* __restrict__ Wfc,  const float* __restrict__ bfc,
    float* __restrict__ out)
{
    const int tid  = threadIdx.x;
    const int lane = tid & 15;
    const int b    = blockIdx.x * 32 + (tid >> 4);

    LOADW(W0, Whh0)   // h0 @ W_hh0^T
    LOADW(W1, Wih1)   // h0n @ W_ih1^T
    LOADW(W2, Whh1)   // h1 @ W_hh1^T

    const float wih0  = Wih0[lane];            // W_ih0 is [16][1]
    const float bias0 = bih0[lane] + bhh0[lane];
    const float bias1 = bih1[lane] + bhh1[lane];

    float h0 = 0.0f, h1 = 0.0f;
    const float* xb = x + (size_t)b * 512;

    // prologue x load; each iteration prefetches the next 16 timesteps
    const float4* xp = reinterpret_cast<const float4*>(xb);
    float4 q0 = xp[0], q1 = xp[1], q2 = xp[2], q3 = xp[3];

    for (int t0 = 0; t0 < 512; t0 += 16) {
        const int tn = (t0 + 16) & 511;   // wraps to 0 on last iter (harmless)
        const float4* xn = reinterpret_cast<const float4*>(xb + tn);
        float4 n0 = xn[0], n1 = xn[1], n2 = xn[2], n3 = xn[3];

        STEP(q0.x) STEP(q0.y) STEP(q0.z) STEP(q0.w)
        STEP(q1.x) STEP(q1.y) STEP(q1.z) STEP(q1.w)
        STEP(q2.x) STEP(q2.y) STEP(q2.z) STEP(q2.w)
        STEP(q3.x) STEP(q3.y) STEP(q3.z) STEP(q3.w)

        q0 = n0; q1 = n1; q2 = n2; q3 = n3;
    }

    // out[b] = h1 . W_fc + b_fc  (builtin DPP path: compiler handles hazards)
    float v = h1 * Wfc[lane];
    v += ROTF(v, 8);
    v += ROTF(v, 4);
    v += ROTF(v, 2);
    v += ROTF(v, 1);
    if (lane == 0) out[b] = v + bfc[0];
}

extern "C" void kernel_launch(void* const* d_in, const int* in_sizes, int n_in,
                              void* d_out, int out_size, void* d_ws, size_t ws_size,
                              hipStream_t stream) {
    const float* x    = (const float*)d_in[0];
    const float* Wih0 = (const float*)d_in[1];
    const float* Whh0 = (const float*)d_in[2];
    const float* bih0 = (const float*)d_in[3];
    const float* bhh0 = (const float*)d_in[4];
    const float* Wih1 = (const float*)d_in[5];
    const float* Whh1 = (const float*)d_in[6];
    const float* bih1 = (const float*)d_in[7];
    const float* bhh1 = (const float*)d_in[8];
    const float* Wfc  = (const float*)d_in[9];
    const float* bfc  = (const float*)d_in[10];
    float* out = (float*)d_out;

    rnn2_kernel<<<dim3(256), dim3(512), 0, stream>>>(
        x, Wih0, Whh0, bih0, bhh0, Wih1, Whh1, bih1, bhh1, Wfc, bfc, out);
}

// Round 4
// 201.043 us; speedup vs baseline: 1.1284x; 1.0077x over previous
//
#include <hip/hip_runtime.h>
#include <hip/hip_fp16.h>

// ---------------------------------------------------------------------------
// 2-layer tanh RNN, B=8192, S=512, H=16. 16 lanes per batch (lane = unit).
// h kept REPLICATED as 8 rotated f16x2 pair-registers per layer:
//   P[i] = (h[i], h[i^1]) packed f16;  R_k[i] = P[(i-2k)&15]  (row_ror:2k).
// Matvec: sum_k v_dot2_f32_f16(Wpk[k], R_k) with per-lane pre-packed weights
//   Wpk[k] = (W[lane][j], W[lane][j^1]), j=(lane-2k)&15  (parity folded in).
// Per step: 2 replications (8 DPP each) + 24 full-rate dot2 + 2 tanh.
// DPP ops measured ~4cyc on gfx950 -> minimize them (was 48/step, now 16).
// 512 threads/block, 256 blocks -> 2048 waves (2/SIMD).
// ---------------------------------------------------------------------------

typedef _Float16 h2_t __attribute__((ext_vector_type(2)));

#define DPPI(v, CTRL) __builtin_amdgcn_update_dpp(0, (int)(v), (CTRL), 0xF, 0xF, true)
// lane i <- lane (i-N)&15 within each 16-lane row
#define RORL(v, N) ((unsigned int)DPPI((v), 0x120 + (N)))
// f32 rotate (for final reduction)
#define ROTF(v, K) __int_as_float(DPPI(__float_as_int(v), 0x120 + (K)))
// lane i <- lane i^1 (quad_perm [1,0,3,2])
#define QSWAP_F(v) __int_as_float(DPPI(__float_as_int(v), 0xB1))

__device__ __forceinline__ float fdot2(unsigned int a, unsigned int b, float c) {
#if __has_builtin(__builtin_amdgcn_fdot2)
    return __builtin_amdgcn_fdot2(__builtin_bit_cast(h2_t, a),
                                  __builtin_bit_cast(h2_t, b), c, false);
#else
    float r;
    asm("v_dot2_f32_f16 %0, %1, %2, %3" : "=v"(r) : "v"(a), "v"(b), "v"(c));
    return r;
#endif
}

__device__ __forceinline__ float tanh_fast(float v) {
    // tanh(v) = 1 - 2/(exp(2v)+1); exp via v_exp_f32 (2^x)
    float e = __builtin_amdgcn_exp2f(v * 2.8853900817779268f);
    float r = __builtin_amdgcn_rcpf(e + 1.0f);
    return fmaf(-2.0f, r, 1.0f);
}

// weight pair for lane, rotation k: (W[lane][j], W[lane][j^1]), RNE-rounded
__device__ __forceinline__ unsigned int pk_w(const float* __restrict__ W,
                                             int lane, int j) {
    unsigned int lo = __half_as_ushort(__float2half_rn(W[lane * 16 + j]));
    unsigned int hi = __half_as_ushort(__float2half_rn(W[lane * 16 + (j ^ 1)]));
    return (hi << 16) | lo;
}

#define LOADW(NAME, SRC)                                             \
  const unsigned int NAME##0 = pk_w((SRC), lane, (lane -  0) & 15);  \
  const unsigned int NAME##1 = pk_w((SRC), lane, (lane -  2) & 15);  \
  const unsigned int NAME##2 = pk_w((SRC), lane, (lane -  4) & 15);  \
  const unsigned int NAME##3 = pk_w((SRC), lane, (lane -  6) & 15);  \
  const unsigned int NAME##4 = pk_w((SRC), lane, (lane -  8) & 15);  \
  const unsigned int NAME##5 = pk_w((SRC), lane, (lane - 10) & 15);  \
  const unsigned int NAME##6 = pk_w((SRC), lane, (lane - 12) & 15);  \
  const unsigned int NAME##7 = pk_w((SRC), lane, (lane - 14) & 15);

// replicate scalar hn (this lane's unit) into 8 rotated f16x2 pair regs
#define REPL(hn, R)                                                  \
  {                                                                  \
    const float nb_ = QSWAP_F(hn);                                   \
    R##0 = __builtin_bit_cast(unsigned int,                          \
             __builtin_amdgcn_cvt_pkrtz((hn), nb_));                 \
    R##1 = RORL(R##0, 2);   R##2 = RORL(R##0, 4);                    \
    R##3 = RORL(R##0, 6);   R##4 = RORL(R##0, 8);                    \
    R##5 = RORL(R##0, 10);  R##6 = RORL(R##0, 12);                   \
    R##7 = RORL(R##0, 14);                                           \
  }

// acc = init + sum_k dot2(W_k, R_k), two chains for ILP
#define MV(NAME, R, init, outv)                          \
  {                                                      \
    float m0_ = fdot2(NAME##0, R##0, (init));            \
    float m1_ = fdot2(NAME##1, R##1, 0.0f);              \
    m0_ = fdot2(NAME##2, R##2, m0_);                     \
    m1_ = fdot2(NAME##3, R##3, m1_);                     \
    m0_ = fdot2(NAME##4, R##4, m0_);                     \
    m1_ = fdot2(NAME##5, R##5, m1_);                     \
    m0_ = fdot2(NAME##6, R##6, m0_);                     \
    m1_ = fdot2(NAME##7, R##7, m1_);                     \
    outv = m0_ + m1_;                                    \
  }

#define STEP(xt)                                   \
  {                                                \
    float a_, c_, d_;                              \
    MV(W0, A, fmaf((xt), wih0, bias0), a_)         \
    MV(W2, B, bias1, c_)                           \
    const float h0n_ = tanh_fast(a_);              \
    REPL(h0n_, A)                                  \
    MV(W1, A, c_, d_)                              \
    h1s = tanh_fast(d_);                           \
    REPL(h1s, B)                                   \
  }

__global__ __launch_bounds__(512, 2) void rnn2_kernel(
    const float* __restrict__ x,
    const float* __restrict__ Wih0, const float* __restrict__ Whh0,
    const float* __restrict__ bih0, const float* __restrict__ bhh0,
    const float* __restrict__ Wih1, const float* __restrict__ Whh1,
    const float* __restrict__ bih1, const float* __restrict__ bhh1,
    const float* __restrict__ Wfc,  const float* __restrict__ bfc,
    float* __restrict__ out)
{
    const int tid  = threadIdx.x;
    const int lane = tid & 15;
    const int b    = blockIdx.x * 32 + (tid >> 4);

    LOADW(W0, Whh0)   // h0  @ W_hh0^T
    LOADW(W1, Wih1)   // h0n @ W_ih1^T
    LOADW(W2, Whh1)   // h1  @ W_hh1^T

    const float wih0  = Wih0[lane];            // W_ih0 is [16][1]
    const float bias0 = bih0[lane] + bhh0[lane];
    const float bias1 = bih1[lane] + bhh1[lane];

    // replicated-h state, zero-initialized
    unsigned int A0 = 0, A1 = 0, A2 = 0, A3 = 0, A4 = 0, A5 = 0, A6 = 0, A7 = 0;
    unsigned int B0 = 0, B1 = 0, B2 = 0, B3 = 0, B4 = 0, B5 = 0, B6 = 0, B7 = 0;
    float h1s = 0.0f;

    const float* xb = x + (size_t)b * 512;
    const float4* xp = reinterpret_cast<const float4*>(xb);
    float4 q0 = xp[0], q1 = xp[1], q2 = xp[2], q3 = xp[3];

    for (int t0 = 0; t0 < 512; t0 += 16) {
        const int tn = (t0 + 16) & 511;   // wraps to 0 on last iter (harmless)
        const float4* xn = reinterpret_cast<const float4*>(xb + tn);
        float4 n0 = xn[0], n1 = xn[1], n2 = xn[2], n3 = xn[3];

        STEP(q0.x) STEP(q0.y) STEP(q0.z) STEP(q0.w)
        STEP(q1.x) STEP(q1.y) STEP(q1.z) STEP(q1.w)
        STEP(q2.x) STEP(q2.y) STEP(q2.z) STEP(q2.w)
        STEP(q3.x) STEP(q3.y) STEP(q3.z) STEP(q3.w)

        q0 = n0; q1 = n1; q2 = n2; q3 = n3;
    }

    // out[b] = h1 . W_fc + b_fc — rotation-based 16-lane reduction
    float v = h1s * Wfc[lane];
    v += ROTF(v, 8);
    v += ROTF(v, 4);
    v += ROTF(v, 2);
    v += ROTF(v, 1);
    if (lane == 0) out[b] = v + bfc[0];
}

extern "C" void kernel_launch(void* const* d_in, const int* in_sizes, int n_in,
                              void* d_out, int out_size, void* d_ws, size_t ws_size,
                              hipStream_t stream) {
    const float* x    = (const float*)d_in[0];
    const float* Wih0 = (const float*)d_in[1];
    const float* Whh0 = (const float*)d_in[2];
    const float* bih0 = (const float*)d_in[3];
    const float* bhh0 = (const float*)d_in[4];
    const float* Wih1 = (const float*)d_in[5];
    const float* Whh1 = (const float*)d_in[6];
    const float* bih1 = (const float*)d_in[7];
    const float* bhh1 = (const float*)d_in[8];
    const float* Wfc  = (const float*)d_in[9];
    const float* bfc  = (const float*)d_in[10];
    float* out = (float*)d_out;

    rnn2_kernel<<<dim3(256), dim3(512), 0, stream>>>(
        x, Wih0, Whh0, bih0, bhh0, Wih1, Whh1, bih1, bhh1, Wfc, bfc, out);
}

// Round 6
// 172.099 us; speedup vs baseline: 1.3182x; 1.1682x over previous
//
#include <hip/hip_runtime.h>
#include <hip/hip_fp16.h>

// ---------------------------------------------------------------------------
// 2-layer tanh RNN, B=8192, S=512, H=16 via MFMA 16x16x16_f16.
// One wave = 16 batch columns. Per step:
//   pre0 = mfma(Whh0, Bh0, Cin)        Cin[r] = wih0[m]*x_t[n] + bias0[m]
//   h0n  = tanh(pre0)  -> pack -> Bh0  (LANE-LOCAL: C rows (l>>4)*4+r match
//   pre1 = mfma(Wih1, Bh0, bias1)       B k-slots (l>>4)*4+i exactly)
//        + mfma(Whh1, Bh1, 0)
//   h1   = tanh(pre1)  -> pack -> Bh1
// Zero cross-lane ops in the loop (the round-2..4 DPP formulations all hit a
// ~270 busy-cyc/step floor; this removes the replication machinery entirely).
// 512 blocks x 64 threads = 512 waves (0.5/SIMD — capped by B/16).
// ---------------------------------------------------------------------------

typedef __fp16 f16x4 __attribute__((ext_vector_type(4)));
typedef __fp16 f16x2 __attribute__((ext_vector_type(2)));
typedef float  f32x4 __attribute__((ext_vector_type(4)));

__device__ __forceinline__ float tanh_fast(float v) {
    // tanh(v) = 1 - 2/(exp(2v)+1); exp via v_exp_f32 (2^x): 2*log2(e)
    float e = __builtin_amdgcn_exp2f(v * 2.8853900817779268f);
    float r = __builtin_amdgcn_rcpf(e + 1.0f);
    return fmaf(-2.0f, r, 1.0f);
}

__global__ __launch_bounds__(64, 1) void rnn2_mfma(
    const float* __restrict__ x,
    const float* __restrict__ Wih0, const float* __restrict__ Whh0,
    const float* __restrict__ bih0, const float* __restrict__ bhh0,
    const float* __restrict__ Wih1, const float* __restrict__ Whh1,
    const float* __restrict__ bih1, const float* __restrict__ bhh1,
    const float* __restrict__ Wfc,  const float* __restrict__ bfc,
    float* __restrict__ out)
{
    const int lane = threadIdx.x & 63;
    const int q    = lane >> 4;     // quarter: k-slot / C-row group
    const int col  = lane & 15;     // batch column n; also A row m
    const int m4   = q * 4;
    const int b0   = blockIdx.x * 16;

    // A fragments: A[m][k], m = col, k = m4 + i  (f16 RNE)
    f16x4 Ahh0, Aih1, Ahh1;
#pragma unroll
    for (int i = 0; i < 4; ++i) {
        Ahh0[i] = (__fp16)Whh0[col * 16 + m4 + i];
        Aih1[i] = (__fp16)Wih1[col * 16 + m4 + i];
        Ahh1[i] = (__fp16)Whh1[col * 16 + m4 + i];
    }
    // per-lane constants for C rows m = m4 + r
    float wih0q[4], b0q[4], wfcq[4];
    f32x4 cb1;
#pragma unroll
    for (int r = 0; r < 4; ++r) {
        wih0q[r] = Wih0[m4 + r];                    // W_ih0 is [16][1]
        b0q[r]   = bih0[m4 + r] + bhh0[m4 + r];
        cb1[r]   = bih1[m4 + r] + bhh1[m4 + r];
        wfcq[r]  = Wfc[m4 + r];
    }
    const float* __restrict__ xrow = x + (size_t)(b0 + col) * 512;

    f16x4 Bh0 = {0, 0, 0, 0}, Bh1 = {0, 0, 0, 0};
    const f32x4 zero4 = {0.f, 0.f, 0.f, 0.f};
    float u0 = 0.f, u1 = 0.f, u2 = 0.f, u3 = 0.f;

    // x values for this lane's batch column, 16-step chunks, prefetched
    float xc[16], xn[16];
#pragma unroll
    for (int i = 0; i < 16; ++i) xc[i] = xrow[i];

    for (int t0 = 0; t0 < 512; t0 += 16) {
        const int tn = (t0 + 16) & 511;   // wraps on last iter (unused values)
#pragma unroll
        for (int i = 0; i < 16; ++i) xn[i] = xrow[tn + i];

#pragma unroll
        for (int j = 0; j < 16; ++j) {
            const float xt = xc[j];
            f32x4 c0;
            c0[0] = fmaf(wih0q[0], xt, b0q[0]);
            c0[1] = fmaf(wih0q[1], xt, b0q[1]);
            c0[2] = fmaf(wih0q[2], xt, b0q[2]);
            c0[3] = fmaf(wih0q[3], xt, b0q[3]);

            // layer 0: pre0 = Whh0 * Bh0 + (x-term + bias)
            f32x4 a = __builtin_amdgcn_mfma_f32_16x16x16f16(Ahh0, Bh0, c0, 0, 0, 0);
            const float s0 = tanh_fast(a[0]);
            const float s1 = tanh_fast(a[1]);
            const float s2 = tanh_fast(a[2]);
            const float s3 = tanh_fast(a[3]);
            f16x2 p0 = __builtin_amdgcn_cvt_pkrtz(s0, s1);
            f16x2 p1 = __builtin_amdgcn_cvt_pkrtz(s2, s3);
            Bh0 = __builtin_shufflevector(p0, p1, 0, 1, 2, 3);

            // layer 1: two independent MFMAs, summed (avoids dependent-C stall)
            f32x4 d = __builtin_amdgcn_mfma_f32_16x16x16f16(Aih1, Bh0, cb1, 0, 0, 0);
            f32x4 e = __builtin_amdgcn_mfma_f32_16x16x16f16(Ahh1, Bh1, zero4, 0, 0, 0);
            u0 = tanh_fast(d[0] + e[0]);
            u1 = tanh_fast(d[1] + e[1]);
            u2 = tanh_fast(d[2] + e[2]);
            u3 = tanh_fast(d[3] + e[3]);
            f16x2 r0 = __builtin_amdgcn_cvt_pkrtz(u0, u1);
            f16x2 r1 = __builtin_amdgcn_cvt_pkrtz(u2, u3);
            Bh1 = __builtin_shufflevector(r0, r1, 0, 1, 2, 3);
        }
#pragma unroll
        for (int i = 0; i < 16; ++i) xc[i] = xn[i];
    }

    // out[b0+n] = Wfc . h1[:,n] + bfc  — partial over this quarter's 4 rows,
    // then sum the 4 quarters (lanes n, n+16, n+32, n+48)
    float v = u0 * wfcq[0] + u1 * wfcq[1] + u2 * wfcq[2] + u3 * wfcq[3];
    v += __shfl_xor(v, 16, 64);
    v += __shfl_xor(v, 32, 64);
    if (lane < 16) out[b0 + lane] = v + bfc[0];
}

extern "C" void kernel_launch(void* const* d_in, const int* in_sizes, int n_in,
                              void* d_out, int out_size, void* d_ws, size_t ws_size,
                              hipStream_t stream) {
    const float* x    = (const float*)d_in[0];
    const float* Wih0 = (const float*)d_in[1];
    const float* Whh0 = (const float*)d_in[2];
    const float* bih0 = (const float*)d_in[3];
    const float* bhh0 = (const float*)d_in[4];
    const float* Wih1 = (const float*)d_in[5];
    const float* Whh1 = (const float*)d_in[6];
    const float* bih1 = (const float*)d_in[7];
    const float* bhh1 = (const float*)d_in[8];
    const float* Wfc  = (const float*)d_in[9];
    const float* bfc  = (const float*)d_in[10];
    float* out = (float*)d_out;

    rnn2_mfma<<<dim3(512), dim3(64), 0, stream>>>(
        x, Wih0, Whh0, bih0, bhh0, Wih1, Whh1, bih1, bhh1, Wfc, bfc, out);
}

// Round 7
// 164.526 us; speedup vs baseline: 1.3789x; 1.0460x over previous
//
#include <hip/hip_runtime.h>
#include <hip/hip_fp16.h>

// ---------------------------------------------------------------------------
// 2-layer tanh RNN, B=8192, S=512, H=16 via MFMA 16x16x16_f16, LAYER-SKEWED.
// One wave = 16 batch columns. Round-6 analysis: 482 cyc/step, pure latency
// bound (issue only ~148). Skew removes the serial layer0->layer1 chain:
// iteration t computes, IN PARALLEL (both read only Bh0=H0[t], Bh1=H1[t-1]):
//   H0[t+1] = tanh(Whh0*H0[t] + c0(x_{t+1}))       (one mfma + tanh)
//   H1[t]   = tanh(Wih1*H0[t] + Whh1*H1[t-1] + b1) (two indep mfma + add + tanh)
// Cross-step CP = one mfma + one tanh + pack. C/D rows (lane>>4)*4+r coincide
// with B k-slots (lane>>4)*4+i, so tanh->pack->next-B is lane-local (no DPP).
// 512 blocks x 64 threads = 512 waves (0.5/SIMD — capped by B/16).
// ---------------------------------------------------------------------------

typedef __fp16 f16x4 __attribute__((ext_vector_type(4)));
typedef __fp16 f16x2 __attribute__((ext_vector_type(2)));
typedef float  f32x4 __attribute__((ext_vector_type(4)));

__device__ __forceinline__ float tanh_fast(float v) {
    // tanh(v) = 1 - 2/(exp(2v)+1); exp via v_exp_f32 (2^x): 2*log2(e)
    float e = __builtin_amdgcn_exp2f(v * 2.8853900817779268f);
    float r = __builtin_amdgcn_rcpf(e + 1.0f);
    return fmaf(-2.0f, r, 1.0f);
}

__global__ __launch_bounds__(64, 1) void rnn2_mfma(
    const float* __restrict__ x,
    const float* __restrict__ Wih0, const float* __restrict__ Whh0,
    const float* __restrict__ bih0, const float* __restrict__ bhh0,
    const float* __restrict__ Wih1, const float* __restrict__ Whh1,
    const float* __restrict__ bih1, const float* __restrict__ bhh1,
    const float* __restrict__ Wfc,  const float* __restrict__ bfc,
    float* __restrict__ out)
{
    const int lane = threadIdx.x & 63;
    const int q    = lane >> 4;     // quarter: k-slot / C-row group
    const int col  = lane & 15;     // batch column n; also A row m
    const int m4   = q * 4;
    const int b0   = blockIdx.x * 16;

    // A fragments: A[m][k], m = col, k = m4 + i  (f16 RNE)
    f16x4 Ahh0, Aih1, Ahh1;
#pragma unroll
    for (int i = 0; i < 4; ++i) {
        Ahh0[i] = (__fp16)Whh0[col * 16 + m4 + i];
        Aih1[i] = (__fp16)Wih1[col * 16 + m4 + i];
        Ahh1[i] = (__fp16)Whh1[col * 16 + m4 + i];
    }
    // per-lane constants for C rows m = m4 + r
    float wih0q[4], b0q[4], wfcq[4];
    f32x4 cb1;
#pragma unroll
    for (int r = 0; r < 4; ++r) {
        wih0q[r] = Wih0[m4 + r];                    // W_ih0 is [16][1]
        b0q[r]   = bih0[m4 + r] + bhh0[m4 + r];
        cb1[r]   = bih1[m4 + r] + bhh1[m4 + r];
        wfcq[r]  = Wfc[m4 + r];
    }
    const float* __restrict__ xrow = x + (size_t)(b0 + col) * 512;

    const f32x4 zero4 = {0.f, 0.f, 0.f, 0.f};
    f16x4 Bh0, Bh1 = {0, 0, 0, 0};
    float u0 = 0.f, u1 = 0.f, u2 = 0.f, u3 = 0.f;

    // x values for this lane's batch column, 16-step chunks, prefetched
    float xc[16], xn[16];
#pragma unroll
    for (int i = 0; i < 16; ++i) xc[i] = xrow[i];

    // ---- prologue: H0[0] = tanh(c0(x_0))  (h0_prev = 0) ----
    {
        const float xt = xc[0];
        const float s0 = tanh_fast(fmaf(wih0q[0], xt, b0q[0]));
        const float s1 = tanh_fast(fmaf(wih0q[1], xt, b0q[1]));
        const float s2 = tanh_fast(fmaf(wih0q[2], xt, b0q[2]));
        const float s3 = tanh_fast(fmaf(wih0q[3], xt, b0q[3]));
        f16x2 p0 = __builtin_amdgcn_cvt_pkrtz(s0, s1);
        f16x2 p1 = __builtin_amdgcn_cvt_pkrtz(s2, s3);
        Bh0 = __builtin_shufflevector(p0, p1, 0, 1, 2, 3);
    }

    // skewed step: consumes Bh0=H0[t], Bh1=H1[t-1]; produces H1[t], H0[t+1]
#define STEP(xt1)                                                             \
  {                                                                           \
    f32x4 c0;                                                                 \
    c0[0] = fmaf(wih0q[0], (xt1), b0q[0]);                                    \
    c0[1] = fmaf(wih0q[1], (xt1), b0q[1]);                                    \
    c0[2] = fmaf(wih0q[2], (xt1), b0q[2]);                                    \
    c0[3] = fmaf(wih0q[3], (xt1), b0q[3]);                                    \
    f32x4 a = __builtin_amdgcn_mfma_f32_16x16x16f16(Ahh0, Bh0, c0, 0, 0, 0);  \
    f32x4 d = __builtin_amdgcn_mfma_f32_16x16x16f16(Aih1, Bh0, cb1, 0, 0, 0); \
    f32x4 e = __builtin_amdgcn_mfma_f32_16x16x16f16(Ahh1, Bh1, zero4, 0, 0, 0);\
    u0 = tanh_fast(d[0] + e[0]);                                              \
    u1 = tanh_fast(d[1] + e[1]);                                              \
    u2 = tanh_fast(d[2] + e[2]);                                              \
    u3 = tanh_fast(d[3] + e[3]);                                              \
    f16x2 r0 = __builtin_amdgcn_cvt_pkrtz(u0, u1);                            \
    f16x2 r1 = __builtin_amdgcn_cvt_pkrtz(u2, u3);                            \
    Bh1 = __builtin_shufflevector(r0, r1, 0, 1, 2, 3);                        \
    const float s0 = tanh_fast(a[0]);                                         \
    const float s1 = tanh_fast(a[1]);                                         \
    const float s2 = tanh_fast(a[2]);                                         \
    const float s3 = tanh_fast(a[3]);                                         \
    f16x2 p0 = __builtin_amdgcn_cvt_pkrtz(s0, s1);                            \
    f16x2 p1 = __builtin_amdgcn_cvt_pkrtz(s2, s3);                            \
    Bh0 = __builtin_shufflevector(p0, p1, 0, 1, 2, 3);                        \
  }

    for (int t0 = 0; t0 < 512; t0 += 16) {
        const int tn = (t0 + 16) & 511;   // wraps on last chunk
#pragma unroll
        for (int i = 0; i < 16; ++i) xn[i] = xrow[tn + i];

        // iteration t = t0+j uses x_{t+1}: xc[j+1] for j<15, else xn[0].
        // Last overall iteration (t=511) uses wrapped xn[0]=x_0 -> computes an
        // UNUSED H0[512]; H1[511] (the u values) is what we keep.
#pragma unroll
        for (int j = 0; j < 16; ++j) {
            const float xt1 = (j < 15) ? xc[j + 1] : xn[0];
            STEP(xt1)
        }
#pragma unroll
        for (int i = 0; i < 16; ++i) xc[i] = xn[i];
    }

    // out[b0+n] = Wfc . H1[511][:,n] + bfc — partial over this quarter's 4
    // rows, then sum quarters (lanes n, n+16, n+32, n+48)
    float v = u0 * wfcq[0] + u1 * wfcq[1] + u2 * wfcq[2] + u3 * wfcq[3];
    v += __shfl_xor(v, 16, 64);
    v += __shfl_xor(v, 32, 64);
    if (lane < 16) out[b0 + lane] = v + bfc[0];
}

extern "C" void kernel_launch(void* const* d_in, const int* in_sizes, int n_in,
                              void* d_out, int out_size, void* d_ws, size_t ws_size,
                              hipStream_t stream) {
    const float* x    = (const float*)d_in[0];
    const float* Wih0 = (const float*)d_in[1];
    const float* Whh0 = (const float*)d_in[2];
    const float* bih0 = (const float*)d_in[3];
    const float* bhh0 = (const float*)d_in[4];
    const float* Wih1 = (const float*)d_in[5];
    const float* Whh1 = (const float*)d_in[6];
    const float* bih1 = (const float*)d_in[7];
    const float* bhh1 = (const float*)d_in[8];
    const float* Wfc  = (const float*)d_in[9];
    const float* bfc  = (const float*)d_in[10];
    float* out = (float*)d_out;

    rnn2_mfma<<<dim3(512), dim3(64), 0, stream>>>(
        x, Wih0, Whh0, bih0, bhh0, Wih1, Whh1, bih1, bhh1, Wfc, bfc, out);
}